// Round 1
// baseline (2332.518 us; speedup 1.0000x reference)
//
#include <hip/hip_runtime.h>
#include <math.h>

#define DIM 1024
#define NH 16
#define HD 64
#define BATCH 4
#define SEQ 4096
#define NTOK (BATCH*SEQ)  // 16384

// ---------------------------------------------------------------------------
// GEMM: C[M,N] = A[M,K] @ B[N,K]^T + bias[N]
// 128x128 tile, BK=16, 256 threads, 8x8 per thread (split 4+4 to avoid LDS
// bank conflicts on the b-operand reads).
// ---------------------------------------------------------------------------
__global__ __launch_bounds__(256) void gemm_nt_bias(
    const float* __restrict__ A, const float* __restrict__ B,
    const float* __restrict__ bias, float* __restrict__ C,
    int M, int N, int K)
{
    __shared__ float As[16][132];
    __shared__ float Bs[16][132];
    const int t  = threadIdx.x;
    const int tx = t & 15;
    const int ty = t >> 4;
    const int m0 = blockIdx.y * 128;
    const int n0 = blockIdx.x * 128;

    float c[8][8];
#pragma unroll
    for (int i = 0; i < 8; i++)
#pragma unroll
        for (int j = 0; j < 8; j++) c[i][j] = 0.f;

    for (int k0 = 0; k0 < K; k0 += 16) {
#pragma unroll
        for (int l = 0; l < 2; l++) {
            int idx = l * 256 + t;
            int row = idx >> 2, seg = idx & 3;
            float4 av = *(const float4*)&A[(size_t)(m0 + row) * K + k0 + seg * 4];
            As[seg * 4 + 0][row] = av.x; As[seg * 4 + 1][row] = av.y;
            As[seg * 4 + 2][row] = av.z; As[seg * 4 + 3][row] = av.w;
            float4 bv = *(const float4*)&B[(size_t)(n0 + row) * K + k0 + seg * 4];
            Bs[seg * 4 + 0][row] = bv.x; Bs[seg * 4 + 1][row] = bv.y;
            Bs[seg * 4 + 2][row] = bv.z; Bs[seg * 4 + 3][row] = bv.w;
        }
        __syncthreads();
#pragma unroll
        for (int kk = 0; kk < 16; kk++) {
            float4 a0 = *(const float4*)&As[kk][ty * 4];
            float4 a1 = *(const float4*)&As[kk][64 + ty * 4];
            float4 b0 = *(const float4*)&Bs[kk][tx * 4];
            float4 b1 = *(const float4*)&Bs[kk][64 + tx * 4];
            float a[8] = {a0.x, a0.y, a0.z, a0.w, a1.x, a1.y, a1.z, a1.w};
            float b[8] = {b0.x, b0.y, b0.z, b0.w, b1.x, b1.y, b1.z, b1.w};
#pragma unroll
            for (int i = 0; i < 8; i++)
#pragma unroll
                for (int j = 0; j < 8; j++)
                    c[i][j] += a[i] * b[j];
        }
        __syncthreads();
    }

    float4 bi0 = *(const float4*)&bias[n0 + tx * 4];
    float4 bi1 = *(const float4*)&bias[n0 + 64 + tx * 4];
    float bb[8] = {bi0.x, bi0.y, bi0.z, bi0.w, bi1.x, bi1.y, bi1.z, bi1.w};
#pragma unroll
    for (int i = 0; i < 8; i++) {
        int row = m0 + ((i < 4) ? (ty * 4 + i) : (64 + ty * 4 + (i - 4)));
        float4 v0 = make_float4(c[i][0] + bb[0], c[i][1] + bb[1],
                                c[i][2] + bb[2], c[i][3] + bb[3]);
        float4 v1 = make_float4(c[i][4] + bb[4], c[i][5] + bb[5],
                                c[i][6] + bb[6], c[i][7] + bb[7]);
        *(float4*)&C[(size_t)row * N + n0 + tx * 4] = v0;
        *(float4*)&C[(size_t)row * N + n0 + 64 + tx * 4] = v1;
    }
}

// ---------------------------------------------------------------------------
// Performer feature map, in place. buf is [262144 rows][64]; each row is one
// (token, head) slice. out = exp((x/8) @ R - 0.5*||x/8||^2)
// One wave per row, 64 rows per block (16 iterations x 4 waves).
// ---------------------------------------------------------------------------
__global__ __launch_bounds__(256) void featmap(
    float* __restrict__ buf, const float* __restrict__ R)
{
    __shared__ float Rs[4096];
    for (int i = threadIdx.x; i < 4096; i += 256) Rs[i] = R[i];
    __syncthreads();
    const int lane = threadIdx.x & 63;
    const int w = threadIdx.x >> 6;
    const size_t base = (size_t)blockIdx.x * 64;
    for (int it = 0; it < 16; it++) {
        size_t row = base + it * 4 + w;
        float qv = buf[row * 64 + lane] * 0.125f;
        float sq = qv * qv;
#pragma unroll
        for (int off = 32; off; off >>= 1) sq += __shfl_xor(sq, off);
        float proj = 0.f;
#pragma unroll
        for (int d = 0; d < 64; d++) proj += __shfl(qv, d) * Rs[d * 64 + lane];
        buf[row * 64 + lane] = __expf(proj - 0.5f * sq);
    }
}

// ---------------------------------------------------------------------------
// kv[b,h,m,e] += sum_n k'[n,m] * v[n,e]  over a 512-token chunk of batch b.
// grid (chunk=8, h=16, b=4); atomicAdd into zeroed kv buffer.
// ---------------------------------------------------------------------------
__global__ __launch_bounds__(256) void kv_accum(
    const float* __restrict__ kp, const float* __restrict__ v,
    float* __restrict__ kv)
{
    __shared__ float Ks[16][68];
    __shared__ float Vs[16][68];
    const int chunk = blockIdx.x;
    const int h = blockIdx.y;
    const int b = blockIdx.z;
    const int t = threadIdx.x;
    const int tx = t & 15, ty = t >> 4;
    float c[4][4] = {};
    const int nbase = b * SEQ + chunk * 512;
    const int nl = t >> 4, seg = t & 15;
    for (int n0 = 0; n0 < 512; n0 += 16) {
        size_t gaddr = (size_t)(nbase + n0 + nl) * DIM + h * 64 + seg * 4;
        float4 kq = *(const float4*)&kp[gaddr];
        float4 vq = *(const float4*)&v[gaddr];
        *(float4*)&Ks[nl][seg * 4] = kq;
        *(float4*)&Vs[nl][seg * 4] = vq;
        __syncthreads();
#pragma unroll
        for (int nn = 0; nn < 16; nn++) {
            float4 a = *(const float4*)&Ks[nn][ty * 4];
            float4 bq = *(const float4*)&Vs[nn][tx * 4];
            float aa[4] = {a.x, a.y, a.z, a.w};
            float bb[4] = {bq.x, bq.y, bq.z, bq.w};
#pragma unroll
            for (int i = 0; i < 4; i++)
#pragma unroll
                for (int j = 0; j < 4; j++)
                    c[i][j] += aa[i] * bb[j];
        }
        __syncthreads();
    }
    float* dst = &kv[(size_t)(b * NH + h) * 64 * 64];
#pragma unroll
    for (int i = 0; i < 4; i++)
#pragma unroll
        for (int j = 0; j < 4; j++)
            atomicAdd(&dst[(ty * 4 + i) * 64 + tx * 4 + j], c[i][j]);
}

// ---------------------------------------------------------------------------
// out[n,h,e] = (1/(sum_m q'[n,h,m] + 1e-8)) * sum_m q'[n,h,m] * kv[b,h,m,e]
// In place over the q' buffer. grid (nchunk=64, bh=64).
// ---------------------------------------------------------------------------
__global__ __launch_bounds__(256) void attn_out(
    float* __restrict__ qp, const float* __restrict__ kv)
{
    __shared__ float kvs[4096];
    const int bh = blockIdx.y;
    const int b = bh >> 4, h = bh & 15;
    for (int i = threadIdx.x; i < 4096; i += 256)
        kvs[i] = kv[(size_t)bh * 4096 + i];
    __syncthreads();
    const int lane = threadIdx.x & 63;
    const int w = threadIdx.x >> 6;
    for (int it = 0; it < 16; it++) {
        int n = b * SEQ + blockIdx.x * 64 + it * 4 + w;
        float* rowp = &qp[(size_t)n * DIM + h * 64];
        float q = rowp[lane];
        float s = q;
#pragma unroll
        for (int off = 32; off; off >>= 1) s += __shfl_xor(s, off);
        float z = 1.f / (s + 1e-8f);
        float acc = 0.f;
#pragma unroll
        for (int m = 0; m < 64; m++) acc += __shfl(q, m) * kvs[m * 64 + lane];
        rowp[lane] = acc * z;
    }
}

extern "C" void kernel_launch(void* const* d_in, const int* in_sizes, int n_in,
                              void* d_out, int out_size, void* d_ws, size_t ws_size,
                              hipStream_t stream) {
    const float* x  = (const float*)d_in[0];
    const float* Wq = (const float*)d_in[1];
    const float* bq = (const float*)d_in[2];
    const float* Wk = (const float*)d_in[3];
    const float* bk = (const float*)d_in[4];
    const float* Wv = (const float*)d_in[5];
    const float* bv = (const float*)d_in[6];
    const float* Wo = (const float*)d_in[7];
    const float* bo = (const float*)d_in[8];
    const float* R  = (const float*)d_in[9];
    float* out = (float*)d_out;

    float* qb  = (float*)d_ws;
    float* kb  = qb + (size_t)NTOK * DIM;
    float* vb  = kb + (size_t)NTOK * DIM;
    float* kvb = vb + (size_t)NTOK * DIM;   // [B*NH][64][64] = 1 MB

    // zero the kv accumulator (ws is poisoned before every call)
    hipMemsetAsync(kvb, 0, (size_t)BATCH * NH * 64 * 64 * sizeof(float), stream);

    dim3 ggrid(DIM / 128, NTOK / 128);  // (8, 128)
    gemm_nt_bias<<<ggrid, 256, 0, stream>>>(x, Wq, bq, qb, NTOK, DIM, DIM);
    gemm_nt_bias<<<ggrid, 256, 0, stream>>>(x, Wk, bk, kb, NTOK, DIM, DIM);
    gemm_nt_bias<<<ggrid, 256, 0, stream>>>(x, Wv, bv, vb, NTOK, DIM, DIM);

    // feature maps in place on q and k ([NTOK*NH] rows of 64)
    featmap<<<NTOK * NH / 64, 256, 0, stream>>>(qb, R);
    featmap<<<NTOK * NH / 64, 256, 0, stream>>>(kb, R);

    kv_accum<<<dim3(8, NH, BATCH), 256, 0, stream>>>(kb, vb, kvb);

    attn_out<<<dim3(SEQ / 64, BATCH * NH), 256, 0, stream>>>(qb, kvb);

    gemm_nt_bias<<<ggrid, 256, 0, stream>>>(qb, Wo, bo, out, NTOK, DIM, DIM);
}

// Round 3
// 1029.721 us; speedup vs baseline: 2.2652x; 2.2652x over previous
//
#include <hip/hip_runtime.h>
#include <math.h>

#define DIM 1024
#define NH 16
#define HD 64
#define BATCH 4
#define SEQ 4096
#define NTOK (BATCH*SEQ)  // 16384

typedef float f32x4 __attribute__((ext_vector_type(4)));
typedef short bf16x8 __attribute__((ext_vector_type(8)));

// LDS dest must be WAVE-UNIFORM base; HW writes base + lane*16B.
#define GLOAD_LDS16(gp, lp)                                                    \
  __builtin_amdgcn_global_load_lds(                                            \
      (const __attribute__((address_space(1))) unsigned int*)(gp),             \
      (__attribute__((address_space(3))) unsigned int*)(lp), 16, 0, 0)

__device__ __forceinline__ unsigned short f2bf(float f) {
  unsigned u = __float_as_uint(f);
  unsigned r = (u + 0x7fffu + ((u >> 16) & 1u)) >> 16;
  return (unsigned short)r;
}
__device__ __forceinline__ float bf2f(unsigned short s) {
  return __uint_as_float((unsigned)s << 16);
}

// ---------------------------------------------------------------------------
// bf16 MFMA GEMM: C[M,N] = A[M,K] @ B[N,K]^T + bias[N]
// 128x128 tile, BK=32, 4 waves, 4x4 mfma_f32_16x16x32_bf16 per wave.
// OUT_BF16=1 -> bf16 output, else fp32.
// ---------------------------------------------------------------------------
template <int OUT_BF16>
__global__ __launch_bounds__(256) void gemm_bt_bf16(
    const unsigned short* __restrict__ A,   // [M][K] bf16
    const unsigned short* __restrict__ B,   // [N][K] bf16
    const float* __restrict__ bias,
    void* __restrict__ Cv, int M, int N, int K)
{
    __shared__ unsigned short As[128 * 32];
    __shared__ unsigned short Bs[128 * 32];
    const int t    = threadIdx.x;
    const int lane = t & 63;
    const int w    = t >> 6;
    const int m0 = blockIdx.y * 128;
    const int n0 = blockIdx.x * 128;
    const int wm = (w >> 1) * 64;
    const int wn = (w & 1) * 64;

    f32x4 acc[4][4] = {};

    // staging: wave w instr i covers rows [i*64 + w*16, +16) of the tile.
    // lane l supplies global row +=(l>>2), col seg (l&3)*8; LDS base uniform.
    const int grow = (lane >> 2);
    const int gcol = (lane & 3) * 8;

    for (int k0 = 0; k0 < K; k0 += 32) {
#pragma unroll
        for (int i = 0; i < 2; i++) {
            int rbase = i * 64 + w * 16;
            GLOAD_LDS16(&A[(size_t)(m0 + rbase + grow) * K + k0 + gcol],
                        &As[rbase * 32]);
            GLOAD_LDS16(&B[(size_t)(n0 + rbase + grow) * K + k0 + gcol],
                        &Bs[rbase * 32]);
        }
        __syncthreads();

        const int fr = lane & 15;
        const int fq = (lane >> 4) * 8;
        bf16x8 af[4], bfr[4];
#pragma unroll
        for (int mt = 0; mt < 4; mt++)
            af[mt] = *(const bf16x8*)&As[(wm + mt * 16 + fr) * 32 + fq];
#pragma unroll
        for (int nt = 0; nt < 4; nt++)
            bfr[nt] = *(const bf16x8*)&Bs[(wn + nt * 16 + fr) * 32 + fq];
#pragma unroll
        for (int mt = 0; mt < 4; mt++)
#pragma unroll
            for (int nt = 0; nt < 4; nt++)
                acc[mt][nt] = __builtin_amdgcn_mfma_f32_16x16x32_bf16(
                    af[mt], bfr[nt], acc[mt][nt], 0, 0, 0);
        __syncthreads();
    }

    // epilogue: C/D layout col = lane&15, row = (lane>>4)*4 + r
    const int col = lane & 15;
    const int rq  = (lane >> 4) * 4;
#pragma unroll
    for (int nt = 0; nt < 4; nt++) {
        int cbase = n0 + wn + nt * 16 + col;
        float bv = bias[cbase];
#pragma unroll
        for (int mt = 0; mt < 4; mt++) {
#pragma unroll
            for (int r = 0; r < 4; r++) {
                int row = m0 + wm + mt * 16 + rq + r;
                float val = acc[mt][nt][r] + bv;
                if (OUT_BF16)
                    ((unsigned short*)Cv)[(size_t)row * N + cbase] = f2bf(val);
                else
                    ((float*)Cv)[(size_t)row * N + cbase] = val;
            }
        }
    }
}

// ---------------------------------------------------------------------------
// fp32 -> bf16 casts
// ---------------------------------------------------------------------------
__global__ __launch_bounds__(256) void cast_bf16(
    const float* __restrict__ src, unsigned short* __restrict__ dst, int n)
{
    int i = (blockIdx.x * 256 + threadIdx.x) * 4;
    if (i >= n) return;
    float4 v = *(const float4*)&src[i];
    ushort2 lo = {f2bf(v.x), f2bf(v.y)};
    ushort2 hi = {f2bf(v.z), f2bf(v.w)};
    *(ushort2*)&dst[i] = lo;
    *(ushort2*)&dst[i + 2] = hi;
}

__global__ __launch_bounds__(256) void cast_bf16_w4(
    const float* __restrict__ s0, const float* __restrict__ s1,
    const float* __restrict__ s2, const float* __restrict__ s3,
    unsigned short* __restrict__ d0, unsigned short* __restrict__ d1,
    unsigned short* __restrict__ d2, unsigned short* __restrict__ d3)
{
    const float* s = (blockIdx.y == 0) ? s0 : (blockIdx.y == 1) ? s1
                    : (blockIdx.y == 2) ? s2 : s3;
    unsigned short* d = (blockIdx.y == 0) ? d0 : (blockIdx.y == 1) ? d1
                       : (blockIdx.y == 2) ? d2 : d3;
    int i = (blockIdx.x * 256 + threadIdx.x) * 4;
    float4 v = *(const float4*)&s[i];
    ushort2 lo = {f2bf(v.x), f2bf(v.y)};
    ushort2 hi = {f2bf(v.z), f2bf(v.w)};
    *(ushort2*)&d[i] = lo;
    *(ushort2*)&d[i + 2] = hi;
}

// ---------------------------------------------------------------------------
// Performer feature map, in place on bf16 buffer (fp32 math).
// One wave per (token,head) row of 64.
// ---------------------------------------------------------------------------
__global__ __launch_bounds__(256) void featmap(
    unsigned short* __restrict__ buf, const float* __restrict__ R)
{
    __shared__ float Rs[4096];
    for (int i = threadIdx.x; i < 4096; i += 256) Rs[i] = R[i];
    __syncthreads();
    const int lane = threadIdx.x & 63;
    const int w = threadIdx.x >> 6;
    const size_t base = (size_t)blockIdx.x * 64;
    for (int it = 0; it < 16; it++) {
        size_t row = base + it * 4 + w;
        float qv = bf2f(buf[row * 64 + lane]) * 0.125f;
        float sq = qv * qv;
#pragma unroll
        for (int off = 32; off; off >>= 1) sq += __shfl_xor(sq, off);
        float proj = 0.f;
#pragma unroll
        for (int d = 0; d < 64; d++) proj += __shfl(qv, d) * Rs[d * 64 + lane];
        buf[row * 64 + lane] = f2bf(__expf(proj - 0.5f * sq));
    }
}

// ---------------------------------------------------------------------------
// kv[b,h,m,e] += sum_n k'[n,m] * v[n,e] over a 512-token chunk. bf16 in.
// ---------------------------------------------------------------------------
__global__ __launch_bounds__(256) void kv_accum(
    const unsigned short* __restrict__ kp, const unsigned short* __restrict__ vp,
    float* __restrict__ kv)
{
    __shared__ float Ks[16][68];
    __shared__ float Vs[16][68];
    const int chunk = blockIdx.x;
    const int h = blockIdx.y;
    const int b = blockIdx.z;
    const int t = threadIdx.x;
    const int tx = t & 15, ty = t >> 4;
    float c[4][4] = {};
    const int nbase = b * SEQ + chunk * 512;
    const int nl = t >> 4, seg = t & 15;
    for (int n0 = 0; n0 < 512; n0 += 16) {
        size_t gaddr = (size_t)(nbase + n0 + nl) * DIM + h * 64 + seg * 4;
        ushort4 kq = *(const ushort4*)&kp[gaddr];
        ushort4 vq = *(const ushort4*)&vp[gaddr];
        Ks[nl][seg * 4 + 0] = bf2f(kq.x); Ks[nl][seg * 4 + 1] = bf2f(kq.y);
        Ks[nl][seg * 4 + 2] = bf2f(kq.z); Ks[nl][seg * 4 + 3] = bf2f(kq.w);
        Vs[nl][seg * 4 + 0] = bf2f(vq.x); Vs[nl][seg * 4 + 1] = bf2f(vq.y);
        Vs[nl][seg * 4 + 2] = bf2f(vq.z); Vs[nl][seg * 4 + 3] = bf2f(vq.w);
        __syncthreads();
#pragma unroll
        for (int nn = 0; nn < 16; nn++) {
            float4 a = *(const float4*)&Ks[nn][ty * 4];
            float4 bq = *(const float4*)&Vs[nn][tx * 4];
            float aa[4] = {a.x, a.y, a.z, a.w};
            float bb[4] = {bq.x, bq.y, bq.z, bq.w};
#pragma unroll
            for (int i = 0; i < 4; i++)
#pragma unroll
                for (int j = 0; j < 4; j++)
                    c[i][j] += aa[i] * bb[j];
        }
        __syncthreads();
    }
    float* dst = &kv[(size_t)(b * NH + h) * 64 * 64];
#pragma unroll
    for (int i = 0; i < 4; i++)
#pragma unroll
        for (int j = 0; j < 4; j++)
            atomicAdd(&dst[(ty * 4 + i) * 64 + tx * 4 + j], c[i][j]);
}

// ---------------------------------------------------------------------------
// out[n,h,e] = z * sum_m q'[n,h,m] * kv[b,h,m,e];  bf16 in q', bf16 out
// ---------------------------------------------------------------------------
__global__ __launch_bounds__(256) void attn_out(
    const unsigned short* __restrict__ qp, const float* __restrict__ kv,
    unsigned short* __restrict__ ob)
{
    __shared__ float kvs[4096];
    const int bh = blockIdx.y;
    const int b = bh >> 4, h = bh & 15;
    for (int i = threadIdx.x; i < 4096; i += 256)
        kvs[i] = kv[(size_t)bh * 4096 + i];
    __syncthreads();
    const int lane = threadIdx.x & 63;
    const int w = threadIdx.x >> 6;
    for (int it = 0; it < 16; it++) {
        int n = b * SEQ + blockIdx.x * 64 + it * 4 + w;
        float q = bf2f(qp[(size_t)n * DIM + h * 64 + lane]);
        float s = q;
#pragma unroll
        for (int off = 32; off; off >>= 1) s += __shfl_xor(s, off);
        float z = 1.f / (s + 1e-8f);
        float acc = 0.f;
#pragma unroll
        for (int m = 0; m < 64; m++) acc += __shfl(q, m) * kvs[m * 64 + lane];
        ob[(size_t)n * DIM + h * 64 + lane] = f2bf(acc * z);
    }
}

extern "C" void kernel_launch(void* const* d_in, const int* in_sizes, int n_in,
                              void* d_out, int out_size, void* d_ws, size_t ws_size,
                              hipStream_t stream) {
    const float* x  = (const float*)d_in[0];
    const float* Wq = (const float*)d_in[1];
    const float* bq = (const float*)d_in[2];
    const float* Wk = (const float*)d_in[3];
    const float* bk = (const float*)d_in[4];
    const float* Wv = (const float*)d_in[5];
    const float* bv = (const float*)d_in[6];
    const float* Wo = (const float*)d_in[7];
    const float* bo = (const float*)d_in[8];
    const float* R  = (const float*)d_in[9];
    float* out = (float*)d_out;

    // workspace layout — total 137 MB (round-1's 193 MB passed; round-2's
    // 265 MB crashed -> keep well under)
    char* p = (char*)d_ws;
    unsigned short* xb = (unsigned short*)p; p += (size_t)NTOK * DIM * 2;  // 32MB
    unsigned short* qb = (unsigned short*)p; p += (size_t)NTOK * DIM * 2;  // 32MB
    unsigned short* kb = (unsigned short*)p; p += (size_t)NTOK * DIM * 2;  // 32MB
    unsigned short* vb = (unsigned short*)p; p += (size_t)NTOK * DIM * 2;  // 32MB
    float* kvb = (float*)p;                  p += (size_t)BATCH * NH * HD * HD * 4; // 1MB
    unsigned short* wqb = (unsigned short*)p; p += (size_t)DIM * DIM * 2;  // 2MB x4
    unsigned short* wkb = (unsigned short*)p; p += (size_t)DIM * DIM * 2;
    unsigned short* wvb = (unsigned short*)p; p += (size_t)DIM * DIM * 2;
    unsigned short* wob = (unsigned short*)p; p += (size_t)DIM * DIM * 2;

    hipMemsetAsync(kvb, 0, (size_t)BATCH * NH * HD * HD * sizeof(float), stream);

    cast_bf16<<<NTOK * DIM / (256 * 4), 256, 0, stream>>>(x, xb, NTOK * DIM);
    cast_bf16_w4<<<dim3(DIM * DIM / (256 * 4), 4), 256, 0, stream>>>(
        Wq, Wk, Wv, Wo, wqb, wkb, wvb, wob);

    dim3 ggrid(DIM / 128, NTOK / 128);  // (8, 128)
    gemm_bt_bf16<1><<<ggrid, 256, 0, stream>>>(xb, wqb, bq, qb, NTOK, DIM, DIM);
    gemm_bt_bf16<1><<<ggrid, 256, 0, stream>>>(xb, wkb, bk, kb, NTOK, DIM, DIM);
    gemm_bt_bf16<1><<<ggrid, 256, 0, stream>>>(xb, wvb, bv, vb, NTOK, DIM, DIM);

    featmap<<<NTOK * NH / 64, 256, 0, stream>>>(qb, R);
    featmap<<<NTOK * NH / 64, 256, 0, stream>>>(kb, R);

    kv_accum<<<dim3(8, NH, BATCH), 256, 0, stream>>>(kb, vb, kvb);

    // attn output reuses xb (x no longer needed after the three projections)
    attn_out<<<dim3(SEQ / 64, BATCH * NH), 256, 0, stream>>>(qb, kvb, xb);

    gemm_bt_bf16<0><<<ggrid, 256, 0, stream>>>(xb, wob, bo, out, NTOK, DIM, DIM);
}

// Round 4
// 679.901 us; speedup vs baseline: 3.4307x; 1.5145x over previous
//
#include <hip/hip_runtime.h>
#include <math.h>

#define DIM 1024
#define NH 16
#define HD 64
#define BATCH 4
#define SEQ 4096
#define NTOK (BATCH*SEQ)  // 16384

typedef float f32x4 __attribute__((ext_vector_type(4)));
typedef short bf16x8 __attribute__((ext_vector_type(8)));

// LDS dest must be WAVE-UNIFORM base; HW writes base + lane*16B.
#define GLOAD_LDS16(gp, lp)                                                    \
  __builtin_amdgcn_global_load_lds(                                            \
      (const __attribute__((address_space(1))) unsigned int*)(gp),             \
      (__attribute__((address_space(3))) unsigned int*)(lp), 16, 0, 0)

__device__ __forceinline__ unsigned short f2bf(float f) {
  unsigned u = __float_as_uint(f);
  unsigned r = (u + 0x7fffu + ((u >> 16) & 1u)) >> 16;
  return (unsigned short)r;
}
__device__ __forceinline__ float bf2f(unsigned short s) {
  return __uint_as_float((unsigned)s << 16);
}

// ---------------------------------------------------------------------------
// bf16 MFMA GEMM: C[M,N] = A[M,K] @ B[N,K]^T + bias[N]
// 128x128 tile, BK=32, 4 waves, 4x4 mfma_f32_16x16x32_bf16 per wave.
// OUT_BF16=1 -> bf16 output, else fp32.
// ---------------------------------------------------------------------------
template <int OUT_BF16>
__global__ __launch_bounds__(256) void gemm_bt_bf16(
    const unsigned short* __restrict__ A,   // [M][K] bf16
    const unsigned short* __restrict__ B,   // [N][K] bf16
    const float* __restrict__ bias,
    void* __restrict__ Cv, int M, int N, int K)
{
    __shared__ unsigned short As[128 * 32];
    __shared__ unsigned short Bs[128 * 32];
    const int t    = threadIdx.x;
    const int lane = t & 63;
    const int w    = t >> 6;
    const int m0 = blockIdx.y * 128;
    const int n0 = blockIdx.x * 128;
    const int wm = (w >> 1) * 64;
    const int wn = (w & 1) * 64;

    f32x4 acc[4][4] = {};

    const int grow = (lane >> 2);
    const int gcol = (lane & 3) * 8;

    for (int k0 = 0; k0 < K; k0 += 32) {
#pragma unroll
        for (int i = 0; i < 2; i++) {
            int rbase = i * 64 + w * 16;
            GLOAD_LDS16(&A[(size_t)(m0 + rbase + grow) * K + k0 + gcol],
                        &As[rbase * 32]);
            GLOAD_LDS16(&B[(size_t)(n0 + rbase + grow) * K + k0 + gcol],
                        &Bs[rbase * 32]);
        }
        __syncthreads();

        const int fr = lane & 15;
        const int fq = (lane >> 4) * 8;
        bf16x8 af[4], bfr[4];
#pragma unroll
        for (int mt = 0; mt < 4; mt++)
            af[mt] = *(const bf16x8*)&As[(wm + mt * 16 + fr) * 32 + fq];
#pragma unroll
        for (int nt = 0; nt < 4; nt++)
            bfr[nt] = *(const bf16x8*)&Bs[(wn + nt * 16 + fr) * 32 + fq];
#pragma unroll
        for (int mt = 0; mt < 4; mt++)
#pragma unroll
            for (int nt = 0; nt < 4; nt++)
                acc[mt][nt] = __builtin_amdgcn_mfma_f32_16x16x32_bf16(
                    af[mt], bfr[nt], acc[mt][nt], 0, 0, 0);
        __syncthreads();
    }

    const int col = lane & 15;
    const int rq  = (lane >> 4) * 4;
#pragma unroll
    for (int nt = 0; nt < 4; nt++) {
        int cbase = n0 + wn + nt * 16 + col;
        float bv = bias[cbase];
#pragma unroll
        for (int mt = 0; mt < 4; mt++) {
#pragma unroll
            for (int r = 0; r < 4; r++) {
                int row = m0 + wm + mt * 16 + rq + r;
                float val = acc[mt][nt][r] + bv;
                if (OUT_BF16)
                    ((unsigned short*)Cv)[(size_t)row * N + cbase] = f2bf(val);
                else
                    ((float*)Cv)[(size_t)row * N + cbase] = val;
            }
        }
    }
}

// ---------------------------------------------------------------------------
// fp32 -> bf16 casts
// ---------------------------------------------------------------------------
__global__ __launch_bounds__(256) void cast_bf16(
    const float* __restrict__ src, unsigned short* __restrict__ dst, int n)
{
    int i = (blockIdx.x * 256 + threadIdx.x) * 4;
    if (i >= n) return;
    float4 v = *(const float4*)&src[i];
    ushort2 lo = {f2bf(v.x), f2bf(v.y)};
    ushort2 hi = {f2bf(v.z), f2bf(v.w)};
    *(ushort2*)&dst[i] = lo;
    *(ushort2*)&dst[i + 2] = hi;
}

__global__ __launch_bounds__(256) void cast_bf16_w4(
    const float* __restrict__ s0, const float* __restrict__ s1,
    const float* __restrict__ s2, const float* __restrict__ s3,
    unsigned short* __restrict__ d0, unsigned short* __restrict__ d1,
    unsigned short* __restrict__ d2, unsigned short* __restrict__ d3)
{
    const float* s = (blockIdx.y == 0) ? s0 : (blockIdx.y == 1) ? s1
                    : (blockIdx.y == 2) ? s2 : s3;
    unsigned short* d = (blockIdx.y == 0) ? d0 : (blockIdx.y == 1) ? d1
                       : (blockIdx.y == 2) ? d2 : d3;
    int i = (blockIdx.x * 256 + threadIdx.x) * 4;
    float4 v = *(const float4*)&s[i];
    ushort2 lo = {f2bf(v.x), f2bf(v.y)};
    ushort2 hi = {f2bf(v.z), f2bf(v.w)};
    *(ushort2*)&d[i] = lo;
    *(ushort2*)&d[i + 2] = hi;
}

// ---------------------------------------------------------------------------
// MFMA Performer feature map, in place on bf16 rows of 64.
// proj = x @ R (MFMA), out = exp(proj/8 - 0.5*||x||^2/64).
// One wave per 64 rows; block = 256 rows; R^T staged bf16 in LDS (stride 72).
// ---------------------------------------------------------------------------
__global__ __launch_bounds__(256) void featmap_mfma(
    unsigned short* __restrict__ buf, const float* __restrict__ R)
{
    __shared__ unsigned short Rt[64 * 72];
    const int t = threadIdx.x;
    for (int i = t; i < 4096; i += 256) {
        int n = i >> 6, k = i & 63;
        Rt[n * 72 + k] = f2bf(R[k * 64 + n]);
    }
    __syncthreads();

    const int lane = t & 63;
    const int w = t >> 6;
    const size_t rowbase = (size_t)blockIdx.x * 256 + w * 64;
    const int fr = lane & 15;
    const int fq = (lane >> 4) * 8;

    f32x4 acc[4][4] = {};
    float sqacc[4] = {0.f, 0.f, 0.f, 0.f};

#pragma unroll
    for (int ks = 0; ks < 2; ks++) {
        bf16x8 bfr[4];
#pragma unroll
        for (int nt = 0; nt < 4; nt++)
            bfr[nt] = *(const bf16x8*)&Rt[(nt * 16 + fr) * 72 + ks * 32 + fq];
#pragma unroll
        for (int mt = 0; mt < 4; mt++) {
            bf16x8 a = *(const bf16x8*)
                &buf[(rowbase + mt * 16 + fr) * 64 + ks * 32 + fq];
#pragma unroll
            for (int j = 0; j < 8; j++) {
                float v = bf2f((unsigned short)a[j]);
                sqacc[mt] = fmaf(v, v, sqacc[mt]);
            }
#pragma unroll
            for (int nt = 0; nt < 4; nt++)
                acc[mt][nt] = __builtin_amdgcn_mfma_f32_16x16x32_bf16(
                    a, bfr[nt], acc[mt][nt], 0, 0, 0);
        }
    }
    // complete ||x||^2 per row: reduce across the 4 k-slices (lane bits 4,5)
#pragma unroll
    for (int mt = 0; mt < 4; mt++) {
        sqacc[mt] += __shfl_xor(sqacc[mt], 16);
        sqacc[mt] += __shfl_xor(sqacc[mt], 32);
    }

    const int col = lane & 15;
    const int rq  = (lane >> 4) * 4;
#pragma unroll
    for (int mt = 0; mt < 4; mt++) {
#pragma unroll
        for (int r = 0; r < 4; r++) {
            float s = __shfl(sqacc[mt], rq + r);   // row mt*16+rq+r
            size_t row = rowbase + mt * 16 + rq + r;
#pragma unroll
            for (int nt = 0; nt < 4; nt++) {
                float val = acc[mt][nt][r] * 0.125f - s * 0.0078125f;
                buf[row * 64 + nt * 16 + col] = f2bf(__expf(val));
            }
        }
    }
}

// ---------------------------------------------------------------------------
// kv[b,h,m,e] += sum_n k'[n,m] * v[n,e] over a 512-token chunk. bf16 in.
// ---------------------------------------------------------------------------
__global__ __launch_bounds__(256) void kv_accum(
    const unsigned short* __restrict__ kp, const unsigned short* __restrict__ vp,
    float* __restrict__ kv)
{
    __shared__ float Ks[16][68];
    __shared__ float Vs[16][68];
    const int chunk = blockIdx.x;
    const int h = blockIdx.y;
    const int b = blockIdx.z;
    const int t = threadIdx.x;
    const int tx = t & 15, ty = t >> 4;
    float c[4][4] = {};
    const int nbase = b * SEQ + chunk * 512;
    const int nl = t >> 4, seg = t & 15;
    for (int n0 = 0; n0 < 512; n0 += 16) {
        size_t gaddr = (size_t)(nbase + n0 + nl) * DIM + h * 64 + seg * 4;
        ushort4 kq = *(const ushort4*)&kp[gaddr];
        ushort4 vq = *(const ushort4*)&vp[gaddr];
        Ks[nl][seg * 4 + 0] = bf2f(kq.x); Ks[nl][seg * 4 + 1] = bf2f(kq.y);
        Ks[nl][seg * 4 + 2] = bf2f(kq.z); Ks[nl][seg * 4 + 3] = bf2f(kq.w);
        Vs[nl][seg * 4 + 0] = bf2f(vq.x); Vs[nl][seg * 4 + 1] = bf2f(vq.y);
        Vs[nl][seg * 4 + 2] = bf2f(vq.z); Vs[nl][seg * 4 + 3] = bf2f(vq.w);
        __syncthreads();
#pragma unroll
        for (int nn = 0; nn < 16; nn++) {
            float4 a = *(const float4*)&Ks[nn][ty * 4];
            float4 bq = *(const float4*)&Vs[nn][tx * 4];
            float aa[4] = {a.x, a.y, a.z, a.w};
            float bb[4] = {bq.x, bq.y, bq.z, bq.w};
#pragma unroll
            for (int i = 0; i < 4; i++)
#pragma unroll
                for (int j = 0; j < 4; j++)
                    c[i][j] += aa[i] * bb[j];
        }
        __syncthreads();
    }
    float* dst = &kv[(size_t)(b * NH + h) * 64 * 64];
#pragma unroll
    for (int i = 0; i < 4; i++)
#pragma unroll
        for (int j = 0; j < 4; j++)
            atomicAdd(&dst[(ty * 4 + i) * 64 + tx * 4 + j], c[i][j]);
}

// ---------------------------------------------------------------------------
// out[n,h,e] = z * sum_m q'[n,h,m] * kv[b,h,m,e];  bf16 in q', bf16 out
// ---------------------------------------------------------------------------
__global__ __launch_bounds__(256) void attn_out(
    const unsigned short* __restrict__ qp, const float* __restrict__ kv,
    unsigned short* __restrict__ ob)
{
    __shared__ float kvs[4096];
    const int bh = blockIdx.y;
    const int b = bh >> 4, h = bh & 15;
    for (int i = threadIdx.x; i < 4096; i += 256)
        kvs[i] = kv[(size_t)bh * 4096 + i];
    __syncthreads();
    const int lane = threadIdx.x & 63;
    const int w = threadIdx.x >> 6;
    for (int it = 0; it < 16; it++) {
        int n = b * SEQ + blockIdx.x * 64 + it * 4 + w;
        float q = bf2f(qp[(size_t)n * DIM + h * 64 + lane]);
        float s = q;
#pragma unroll
        for (int off = 32; off; off >>= 1) s += __shfl_xor(s, off);
        float z = 1.f / (s + 1e-8f);
        float acc = 0.f;
#pragma unroll
        for (int m = 0; m < 64; m++) acc += __shfl(q, m) * kvs[m * 64 + lane];
        ob[(size_t)n * DIM + h * 64 + lane] = f2bf(acc * z);
    }
}

extern "C" void kernel_launch(void* const* d_in, const int* in_sizes, int n_in,
                              void* d_out, int out_size, void* d_ws, size_t ws_size,
                              hipStream_t stream) {
    const float* x  = (const float*)d_in[0];
    const float* Wq = (const float*)d_in[1];
    const float* bq = (const float*)d_in[2];
    const float* Wk = (const float*)d_in[3];
    const float* bk = (const float*)d_in[4];
    const float* Wv = (const float*)d_in[5];
    const float* bv = (const float*)d_in[6];
    const float* Wo = (const float*)d_in[7];
    const float* bo = (const float*)d_in[8];
    const float* R  = (const float*)d_in[9];
    float* out = (float*)d_out;

    // workspace layout — 137 MB total. qb and kb MUST stay adjacent
    // (featmap_mfma runs over them as one contiguous region).
    char* p = (char*)d_ws;
    unsigned short* xb = (unsigned short*)p; p += (size_t)NTOK * DIM * 2;  // 32MB
    unsigned short* qb = (unsigned short*)p; p += (size_t)NTOK * DIM * 2;  // 32MB
    unsigned short* kb = (unsigned short*)p; p += (size_t)NTOK * DIM * 2;  // 32MB
    unsigned short* vb = (unsigned short*)p; p += (size_t)NTOK * DIM * 2;  // 32MB
    float* kvb = (float*)p;                  p += (size_t)BATCH * NH * HD * HD * 4; // 1MB
    unsigned short* wqb = (unsigned short*)p; p += (size_t)DIM * DIM * 2;  // 2MB x4
    unsigned short* wkb = (unsigned short*)p; p += (size_t)DIM * DIM * 2;
    unsigned short* wvb = (unsigned short*)p; p += (size_t)DIM * DIM * 2;
    unsigned short* wob = (unsigned short*)p; p += (size_t)DIM * DIM * 2;

    hipMemsetAsync(kvb, 0, (size_t)BATCH * NH * HD * HD * sizeof(float), stream);

    cast_bf16<<<NTOK * DIM / (256 * 4), 256, 0, stream>>>(x, xb, NTOK * DIM);
    cast_bf16_w4<<<dim3(DIM * DIM / (256 * 4), 4), 256, 0, stream>>>(
        Wq, Wk, Wv, Wo, wqb, wkb, wvb, wob);

    dim3 ggrid(DIM / 128, NTOK / 128);  // (8, 128)
    gemm_bt_bf16<1><<<ggrid, 256, 0, stream>>>(xb, wqb, bq, qb, NTOK, DIM, DIM);
    gemm_bt_bf16<1><<<ggrid, 256, 0, stream>>>(xb, wkb, bk, kb, NTOK, DIM, DIM);
    gemm_bt_bf16<1><<<ggrid, 256, 0, stream>>>(xb, wvb, bv, vb, NTOK, DIM, DIM);

    // feature map over q' and k' in one launch (contiguous 524288 rows)
    featmap_mfma<<<2 * NTOK * NH / 256, 256, 0, stream>>>(qb, R);

    kv_accum<<<dim3(8, NH, BATCH), 256, 0, stream>>>(kb, vb, kvb);

    attn_out<<<dim3(SEQ / 64, BATCH * NH), 256, 0, stream>>>(qb, kvb, xb);

    gemm_bt_bf16<0><<<ggrid, 256, 0, stream>>>(xb, wob, bo, out, NTOK, DIM, DIM);
}

// Round 5
// 496.606 us; speedup vs baseline: 4.6969x; 1.3691x over previous
//
#include <hip/hip_runtime.h>
#include <math.h>

#define DIM 1024
#define NH 16
#define HD 64
#define BATCH 4
#define SEQ 4096
#define NTOK (BATCH*SEQ)  // 16384

typedef float f32x4 __attribute__((ext_vector_type(4)));
typedef short bf16x8 __attribute__((ext_vector_type(8)));

// LDS dest must be WAVE-UNIFORM base; HW writes base + lane*16B.
#define GLOAD_LDS16(gp, lp)                                                    \
  __builtin_amdgcn_global_load_lds(                                            \
      (const __attribute__((address_space(1))) unsigned int*)(gp),             \
      (__attribute__((address_space(3))) unsigned int*)(lp), 16, 0, 0)

__device__ __forceinline__ unsigned short f2bf(float f) {
  unsigned u = __float_as_uint(f);
  unsigned r = (u + 0x7fffu + ((u >> 16) & 1u)) >> 16;
  return (unsigned short)r;
}
__device__ __forceinline__ float bf2f(unsigned short s) {
  return __uint_as_float((unsigned)s << 16);
}

// ---------------------------------------------------------------------------
// bf16 MFMA GEMM: C[M,N] = A[M,K] @ B[N,K]^T + bias[N]
// 128x128 tile, BK=32, 4 waves, 4x4 mfma_f32_16x16x32_bf16 per wave.
// OUT_BF16=1 -> bf16 output, else fp32.
// ---------------------------------------------------------------------------
template <int OUT_BF16>
__global__ __launch_bounds__(256) void gemm_bt_bf16(
    const unsigned short* __restrict__ A,   // [M][K] bf16
    const unsigned short* __restrict__ B,   // [N][K] bf16
    const float* __restrict__ bias,
    void* __restrict__ Cv, int M, int N, int K)
{
    __shared__ unsigned short As[128 * 32];
    __shared__ unsigned short Bs[128 * 32];
    const int t    = threadIdx.x;
    const int lane = t & 63;
    const int w    = t >> 6;
    const int m0 = blockIdx.y * 128;
    const int n0 = blockIdx.x * 128;
    const int wm = (w >> 1) * 64;
    const int wn = (w & 1) * 64;

    f32x4 acc[4][4] = {};

    const int grow = (lane >> 2);
    const int gcol = (lane & 3) * 8;

    for (int k0 = 0; k0 < K; k0 += 32) {
#pragma unroll
        for (int i = 0; i < 2; i++) {
            int rbase = i * 64 + w * 16;
            GLOAD_LDS16(&A[(size_t)(m0 + rbase + grow) * K + k0 + gcol],
                        &As[rbase * 32]);
            GLOAD_LDS16(&B[(size_t)(n0 + rbase + grow) * K + k0 + gcol],
                        &Bs[rbase * 32]);
        }
        __syncthreads();

        const int fr = lane & 15;
        const int fq = (lane >> 4) * 8;
        bf16x8 af[4], bfr[4];
#pragma unroll
        for (int mt = 0; mt < 4; mt++)
            af[mt] = *(const bf16x8*)&As[(wm + mt * 16 + fr) * 32 + fq];
#pragma unroll
        for (int nt = 0; nt < 4; nt++)
            bfr[nt] = *(const bf16x8*)&Bs[(wn + nt * 16 + fr) * 32 + fq];
#pragma unroll
        for (int mt = 0; mt < 4; mt++)
#pragma unroll
            for (int nt = 0; nt < 4; nt++)
                acc[mt][nt] = __builtin_amdgcn_mfma_f32_16x16x32_bf16(
                    af[mt], bfr[nt], acc[mt][nt], 0, 0, 0);
        __syncthreads();
    }

    const int col = lane & 15;
    const int rq  = (lane >> 4) * 4;
#pragma unroll
    for (int nt = 0; nt < 4; nt++) {
        int cbase = n0 + wn + nt * 16 + col;
        float bv = bias[cbase];
#pragma unroll
        for (int mt = 0; mt < 4; mt++) {
#pragma unroll
            for (int r = 0; r < 4; r++) {
                int row = m0 + wm + mt * 16 + rq + r;
                float val = acc[mt][nt][r] + bv;
                if (OUT_BF16)
                    ((unsigned short*)Cv)[(size_t)row * N + cbase] = f2bf(val);
                else
                    ((float*)Cv)[(size_t)row * N + cbase] = val;
            }
        }
    }
}

// ---------------------------------------------------------------------------
// fp32 -> bf16 casts
// ---------------------------------------------------------------------------
__global__ __launch_bounds__(256) void cast_bf16(
    const float* __restrict__ src, unsigned short* __restrict__ dst, int n)
{
    int i = (blockIdx.x * 256 + threadIdx.x) * 4;
    if (i >= n) return;
    float4 v = *(const float4*)&src[i];
    ushort2 lo = {f2bf(v.x), f2bf(v.y)};
    ushort2 hi = {f2bf(v.z), f2bf(v.w)};
    *(ushort2*)&dst[i] = lo;
    *(ushort2*)&dst[i + 2] = hi;
}

__global__ __launch_bounds__(256) void cast_bf16_w4(
    const float* __restrict__ s0, const float* __restrict__ s1,
    const float* __restrict__ s2, const float* __restrict__ s3,
    unsigned short* __restrict__ d0, unsigned short* __restrict__ d1,
    unsigned short* __restrict__ d2, unsigned short* __restrict__ d3)
{
    const float* s = (blockIdx.y == 0) ? s0 : (blockIdx.y == 1) ? s1
                    : (blockIdx.y == 2) ? s2 : s3;
    unsigned short* d = (blockIdx.y == 0) ? d0 : (blockIdx.y == 1) ? d1
                       : (blockIdx.y == 2) ? d2 : d3;
    int i = (blockIdx.x * 256 + threadIdx.x) * 4;
    float4 v = *(const float4*)&s[i];
    ushort2 lo = {f2bf(v.x), f2bf(v.y)};
    ushort2 hi = {f2bf(v.z), f2bf(v.w)};
    *(ushort2*)&d[i] = lo;
    *(ushort2*)&d[i + 2] = hi;
}

// ---------------------------------------------------------------------------
// MFMA Performer feature map, in place on bf16 rows of 64.
// proj = x @ R (MFMA), out = exp(proj/8 - 0.5*||x||^2/64).
// One wave per 64 rows; block = 256 rows; R^T staged bf16 in LDS (stride 72).
// ---------------------------------------------------------------------------
__global__ __launch_bounds__(256) void featmap_mfma(
    unsigned short* __restrict__ buf, const float* __restrict__ R)
{
    __shared__ unsigned short Rt[64 * 72];
    const int t = threadIdx.x;
    for (int i = t; i < 4096; i += 256) {
        int n = i >> 6, k = i & 63;
        Rt[n * 72 + k] = f2bf(R[k * 64 + n]);
    }
    __syncthreads();

    const int lane = t & 63;
    const int w = t >> 6;
    const size_t rowbase = (size_t)blockIdx.x * 256 + w * 64;
    const int fr = lane & 15;
    const int fq = (lane >> 4) * 8;

    f32x4 acc[4][4] = {};
    float sqacc[4] = {0.f, 0.f, 0.f, 0.f};

#pragma unroll
    for (int ks = 0; ks < 2; ks++) {
        bf16x8 bfr[4];
#pragma unroll
        for (int nt = 0; nt < 4; nt++)
            bfr[nt] = *(const bf16x8*)&Rt[(nt * 16 + fr) * 72 + ks * 32 + fq];
#pragma unroll
        for (int mt = 0; mt < 4; mt++) {
            bf16x8 a = *(const bf16x8*)
                &buf[(rowbase + mt * 16 + fr) * 64 + ks * 32 + fq];
#pragma unroll
            for (int j = 0; j < 8; j++) {
                float v = bf2f((unsigned short)a[j]);
                sqacc[mt] = fmaf(v, v, sqacc[mt]);
            }
#pragma unroll
            for (int nt = 0; nt < 4; nt++)
                acc[mt][nt] = __builtin_amdgcn_mfma_f32_16x16x32_bf16(
                    a, bfr[nt], acc[mt][nt], 0, 0, 0);
        }
    }
    // complete ||x||^2 per row: reduce across the 4 k-slices (lane bits 4,5)
#pragma unroll
    for (int mt = 0; mt < 4; mt++) {
        sqacc[mt] += __shfl_xor(sqacc[mt], 16);
        sqacc[mt] += __shfl_xor(sqacc[mt], 32);
    }

    const int col = lane & 15;
    const int rq  = (lane >> 4) * 4;
#pragma unroll
    for (int mt = 0; mt < 4; mt++) {
#pragma unroll
        for (int r = 0; r < 4; r++) {
            float s = __shfl(sqacc[mt], rq + r);   // row mt*16+rq+r
            size_t row = rowbase + mt * 16 + rq + r;
#pragma unroll
            for (int nt = 0; nt < 4; nt++) {
                float val = acc[mt][nt][r] * 0.125f - s * 0.0078125f;
                buf[row * 64 + nt * 16 + col] = f2bf(__expf(val));
            }
        }
    }
}

// ---------------------------------------------------------------------------
// kv[b,h,m,e] += sum_n k'[n,m] * v[n,e] over a 512-token chunk. bf16 in.
// ---------------------------------------------------------------------------
__global__ __launch_bounds__(256) void kv_accum(
    const unsigned short* __restrict__ kp, const unsigned short* __restrict__ vp,
    float* __restrict__ kv)
{
    __shared__ float Ks[16][68];
    __shared__ float Vs[16][68];
    const int chunk = blockIdx.x;
    const int h = blockIdx.y;
    const int b = blockIdx.z;
    const int t = threadIdx.x;
    const int tx = t & 15, ty = t >> 4;
    float c[4][4] = {};
    const int nbase = b * SEQ + chunk * 512;
    const int nl = t >> 4, seg = t & 15;
    for (int n0 = 0; n0 < 512; n0 += 16) {
        size_t gaddr = (size_t)(nbase + n0 + nl) * DIM + h * 64 + seg * 4;
        ushort4 kq = *(const ushort4*)&kp[gaddr];
        ushort4 vq = *(const ushort4*)&vp[gaddr];
        Ks[nl][seg * 4 + 0] = bf2f(kq.x); Ks[nl][seg * 4 + 1] = bf2f(kq.y);
        Ks[nl][seg * 4 + 2] = bf2f(kq.z); Ks[nl][seg * 4 + 3] = bf2f(kq.w);
        Vs[nl][seg * 4 + 0] = bf2f(vq.x); Vs[nl][seg * 4 + 1] = bf2f(vq.y);
        Vs[nl][seg * 4 + 2] = bf2f(vq.z); Vs[nl][seg * 4 + 3] = bf2f(vq.w);
        __syncthreads();
#pragma unroll
        for (int nn = 0; nn < 16; nn++) {
            float4 a = *(const float4*)&Ks[nn][ty * 4];
            float4 bq = *(const float4*)&Vs[nn][tx * 4];
            float aa[4] = {a.x, a.y, a.z, a.w};
            float bb[4] = {bq.x, bq.y, bq.z, bq.w};
#pragma unroll
            for (int i = 0; i < 4; i++)
#pragma unroll
                for (int j = 0; j < 4; j++)
                    c[i][j] += aa[i] * bb[j];
        }
        __syncthreads();
    }
    float* dst = &kv[(size_t)(b * NH + h) * 64 * 64];
#pragma unroll
    for (int i = 0; i < 4; i++)
#pragma unroll
        for (int j = 0; j < 4; j++)
            atomicAdd(&dst[(ty * 4 + i) * 64 + tx * 4 + j], c[i][j]);
}

// ---------------------------------------------------------------------------
// MFMA attn out: per (b,h), out[n,e] = z[n] * (q'[n,:] @ kv[:,e]),
// z[n] = 1/(sum_m q'[n,m] + 1e-8).  kv staged transposed bf16 in LDS
// (B-operand layout B[e][m] = kv[m][e]).  One wave per 64 rows; bf16 out.
// ---------------------------------------------------------------------------
__global__ __launch_bounds__(256) void attn_out_mfma(
    const unsigned short* __restrict__ qp, const float* __restrict__ kv,
    unsigned short* __restrict__ ob)
{
    __shared__ unsigned short kvT[64 * 72];
    const int t = threadIdx.x;
    const int bh = blockIdx.y;
    const int b = bh >> 4, h = bh & 15;
    const float* kvp = &kv[(size_t)bh * 4096];
    for (int i = t; i < 4096; i += 256) {
        int m = i >> 6, e = i & 63;
        kvT[e * 72 + m] = f2bf(kvp[i]);
    }
    __syncthreads();

    const int lane = t & 63;
    const int w = t >> 6;
    const int rowInSeq = blockIdx.x * 256 + w * 64;
    const int fr = lane & 15;
    const int fq = (lane >> 4) * 8;

    f32x4 acc[4][4] = {};
    float rsum[4] = {0.f, 0.f, 0.f, 0.f};

#pragma unroll
    for (int ks = 0; ks < 2; ks++) {
        bf16x8 bfr[4];
#pragma unroll
        for (int nt = 0; nt < 4; nt++)
            bfr[nt] = *(const bf16x8*)&kvT[(nt * 16 + fr) * 72 + ks * 32 + fq];
#pragma unroll
        for (int mt = 0; mt < 4; mt++) {
            size_t n = (size_t)(b * SEQ + rowInSeq + mt * 16 + fr);
            bf16x8 a = *(const bf16x8*)&qp[n * DIM + h * 64 + ks * 32 + fq];
#pragma unroll
            for (int j = 0; j < 8; j++)
                rsum[mt] += bf2f((unsigned short)a[j]);
#pragma unroll
            for (int nt = 0; nt < 4; nt++)
                acc[mt][nt] = __builtin_amdgcn_mfma_f32_16x16x32_bf16(
                    a, bfr[nt], acc[mt][nt], 0, 0, 0);
        }
    }
    // per-row denominator: reduce across the 4 k-slices (lane bits 4,5)
#pragma unroll
    for (int mt = 0; mt < 4; mt++) {
        rsum[mt] += __shfl_xor(rsum[mt], 16);
        rsum[mt] += __shfl_xor(rsum[mt], 32);
    }

    const int col = lane & 15;
    const int rq  = (lane >> 4) * 4;
#pragma unroll
    for (int mt = 0; mt < 4; mt++) {
#pragma unroll
        for (int r = 0; r < 4; r++) {
            float s = __shfl(rsum[mt], rq + r);
            float z = 1.f / (s + 1e-8f);
            size_t n = (size_t)(b * SEQ + rowInSeq + mt * 16 + rq + r);
#pragma unroll
            for (int nt = 0; nt < 4; nt++)
                ob[n * DIM + h * 64 + nt * 16 + col] = f2bf(acc[mt][nt][r] * z);
        }
    }
}

extern "C" void kernel_launch(void* const* d_in, const int* in_sizes, int n_in,
                              void* d_out, int out_size, void* d_ws, size_t ws_size,
                              hipStream_t stream) {
    const float* x  = (const float*)d_in[0];
    const float* Wq = (const float*)d_in[1];
    const float* bq = (const float*)d_in[2];
    const float* Wk = (const float*)d_in[3];
    const float* bk = (const float*)d_in[4];
    const float* Wv = (const float*)d_in[5];
    const float* bv = (const float*)d_in[6];
    const float* Wo = (const float*)d_in[7];
    const float* bo = (const float*)d_in[8];
    const float* R  = (const float*)d_in[9];
    float* out = (float*)d_out;

    // workspace layout — 137 MB total. qb and kb MUST stay adjacent
    // (featmap_mfma runs over them as one contiguous region).
    char* p = (char*)d_ws;
    unsigned short* xb = (unsigned short*)p; p += (size_t)NTOK * DIM * 2;  // 32MB
    unsigned short* qb = (unsigned short*)p; p += (size_t)NTOK * DIM * 2;  // 32MB
    unsigned short* kb = (unsigned short*)p; p += (size_t)NTOK * DIM * 2;  // 32MB
    unsigned short* vb = (unsigned short*)p; p += (size_t)NTOK * DIM * 2;  // 32MB
    float* kvb = (float*)p;                  p += (size_t)BATCH * NH * HD * HD * 4; // 1MB
    unsigned short* wqb = (unsigned short*)p; p += (size_t)DIM * DIM * 2;  // 2MB x4
    unsigned short* wkb = (unsigned short*)p; p += (size_t)DIM * DIM * 2;
    unsigned short* wvb = (unsigned short*)p; p += (size_t)DIM * DIM * 2;
    unsigned short* wob = (unsigned short*)p; p += (size_t)DIM * DIM * 2;

    hipMemsetAsync(kvb, 0, (size_t)BATCH * NH * HD * HD * sizeof(float), stream);

    cast_bf16<<<NTOK * DIM / (256 * 4), 256, 0, stream>>>(x, xb, NTOK * DIM);
    cast_bf16_w4<<<dim3(DIM * DIM / (256 * 4), 4), 256, 0, stream>>>(
        Wq, Wk, Wv, Wo, wqb, wkb, wvb, wob);

    dim3 ggrid(DIM / 128, NTOK / 128);  // (8, 128)
    gemm_bt_bf16<1><<<ggrid, 256, 0, stream>>>(xb, wqb, bq, qb, NTOK, DIM, DIM);
    gemm_bt_bf16<1><<<ggrid, 256, 0, stream>>>(xb, wkb, bk, kb, NTOK, DIM, DIM);
    gemm_bt_bf16<1><<<ggrid, 256, 0, stream>>>(xb, wvb, bv, vb, NTOK, DIM, DIM);

    // feature map over q' and k' in one launch (contiguous 524288 rows)
    featmap_mfma<<<2 * NTOK * NH / 256, 256, 0, stream>>>(qb, R);

    kv_accum<<<dim3(8, NH, BATCH), 256, 0, stream>>>(kb, vb, kvb);

    // attn output reuses xb (x no longer needed after the three projections)
    attn_out_mfma<<<dim3(SEQ / 256, BATCH * NH), 256, 0, stream>>>(qb, kvb, xb);

    gemm_bt_bf16<0><<<ggrid, 256, 0, stream>>>(xb, wob, bo, out, NTOK, DIM, DIM);
}

// Round 6
// 424.148 us; speedup vs baseline: 5.4993x; 1.1708x over previous
//
#include <hip/hip_runtime.h>
#include <math.h>

#define DIM 1024
#define NH 16
#define HD 64
#define BATCH 4
#define SEQ 4096
#define NTOK (BATCH*SEQ)  // 16384

typedef float f32x4 __attribute__((ext_vector_type(4)));
typedef short bf16x8 __attribute__((ext_vector_type(8)));

// LDS dest must be WAVE-UNIFORM base; HW writes base + lane*16B.
#define GLOAD_LDS16(gp, lp)                                                    \
  __builtin_amdgcn_global_load_lds(                                            \
      (const __attribute__((address_space(1))) unsigned int*)(gp),             \
      (__attribute__((address_space(3))) unsigned int*)(lp), 16, 0, 0)

__device__ __forceinline__ unsigned short f2bf(float f) {
  unsigned u = __float_as_uint(f);
  unsigned r = (u + 0x7fffu + ((u >> 16) & 1u)) >> 16;
  return (unsigned short)r;
}
__device__ __forceinline__ float bf2f(unsigned short s) {
  return __uint_as_float((unsigned)s << 16);
}

// ---------------------------------------------------------------------------
// bf16 MFMA GEMM, bank-conflict-free + XCD-swizzled.
//   C = A[16384,1024] @ B[NB_N*128,1024]^T + bias
// NB_N = n-blocks (24 = fused QKV vs wqkv concat; 8 = O-proj).
// XOR-swizzle: row R's k-chunk c lives at LDS chunk c^((R>>1)&3) -> the
// 16-lane read phases spread over all 8 bank groups (2-way = free) instead
// of 4-way conflicts (was exactly 4 extra cyc x 2^20 reads = 2^22 counter).
// XCD swizzle: bid&7 = XCD owns 16 consecutive m-tiles -> A-tile fetched
// once per XCD instead of 8/24 XCD-scattered re-fetches.
// ---------------------------------------------------------------------------
template <int NB_N, int OUT_BF16>
__global__ __launch_bounds__(256) void gemm_swz(
    const unsigned short* __restrict__ A,
    const unsigned short* __restrict__ B,
    const float* __restrict__ b0, const float* __restrict__ b1,
    const float* __restrict__ b2,
    void* __restrict__ C0, void* __restrict__ C1, void* __restrict__ C2)
{
    __shared__ unsigned short As[128 * 32];
    __shared__ unsigned short Bs[128 * 32];
    const int t    = threadIdx.x;
    const int lane = t & 63;
    const int w    = t >> 6;

    const int bid   = blockIdx.x;
    const int xcd   = bid & 7;
    const int local = bid >> 3;
    const int mi    = xcd * 16 + local / NB_N;   // m-tile 0..127
    const int ni    = local % NB_N;              // n-block
    const int m0    = mi * 128;
    const int n0g   = ni * 128;                  // row into concat B

    const int wm = (w >> 1) * 64;
    const int wn = (w & 1) * 64;

    f32x4 acc[4][4] = {};

    // staging: lane l -> rel row l>>2, stores global seg (l&3)^((l>>3)&3)
    // at LDS chunk (l&3)  [ (l>>3)&3 == (rel_row>>1)&3 ]
    const int srow = lane >> 2;
    const int sseg = ((lane & 3) ^ ((lane >> 3) & 3)) * 8;

    // fragment read: row fr's k-chunk q8 sits at LDS chunk q8^((fr>>1)&3)
    const int fr = lane & 15;
    const int q8 = lane >> 4;
    const int fq = (q8 ^ ((fr >> 1) & 3)) * 8;

    for (int k0 = 0; k0 < 1024; k0 += 32) {
#pragma unroll
        for (int i = 0; i < 2; i++) {
            int rbase = i * 64 + w * 16;
            GLOAD_LDS16(&A[(size_t)(m0 + rbase + srow) * 1024 + k0 + sseg],
                        &As[rbase * 32]);
            GLOAD_LDS16(&B[(size_t)(n0g + rbase + srow) * 1024 + k0 + sseg],
                        &Bs[rbase * 32]);
        }
        __syncthreads();

        bf16x8 af[4], bfr[4];
#pragma unroll
        for (int mt = 0; mt < 4; mt++)
            af[mt] = *(const bf16x8*)&As[(wm + mt * 16 + fr) * 32 + fq];
#pragma unroll
        for (int nt = 0; nt < 4; nt++)
            bfr[nt] = *(const bf16x8*)&Bs[(wn + nt * 16 + fr) * 32 + fq];
#pragma unroll
        for (int mt = 0; mt < 4; mt++)
#pragma unroll
            for (int nt = 0; nt < 4; nt++)
                acc[mt][nt] = __builtin_amdgcn_mfma_f32_16x16x32_bf16(
                    af[mt], bfr[nt], acc[mt][nt], 0, 0, 0);
        __syncthreads();
    }

    // epilogue: select matrix (uniform per block), C/D layout col=lane&15,
    // row=(lane>>4)*4+r.  Outputs are separate [16384][1024] buffers.
    const int mat = ni >> 3;
    const float* bias = (NB_N == 8) ? b0 : (mat == 0 ? b0 : mat == 1 ? b1 : b2);
    void* Cp = (NB_N == 8) ? C0 : (mat == 0 ? C0 : mat == 1 ? C1 : C2);
    const int n0 = (ni & 7) * 128;

    const int col = lane & 15;
    const int rq  = (lane >> 4) * 4;
#pragma unroll
    for (int nt = 0; nt < 4; nt++) {
        int cbase = n0 + wn + nt * 16 + col;
        float bv = bias[cbase];
#pragma unroll
        for (int mt = 0; mt < 4; mt++) {
#pragma unroll
            for (int r = 0; r < 4; r++) {
                int row = m0 + wm + mt * 16 + rq + r;
                float val = acc[mt][nt][r] + bv;
                if (OUT_BF16)
                    ((unsigned short*)Cp)[(size_t)row * 1024 + cbase] = f2bf(val);
                else
                    ((float*)Cp)[(size_t)row * 1024 + cbase] = val;
            }
        }
    }
}

// ---------------------------------------------------------------------------
// fp32 -> bf16 casts
// ---------------------------------------------------------------------------
__global__ __launch_bounds__(256) void cast_bf16(
    const float* __restrict__ src, unsigned short* __restrict__ dst, int n)
{
    int i = (blockIdx.x * 256 + threadIdx.x) * 4;
    if (i >= n) return;
    float4 v = *(const float4*)&src[i];
    ushort2 lo = {f2bf(v.x), f2bf(v.y)};
    ushort2 hi = {f2bf(v.z), f2bf(v.w)};
    *(ushort2*)&dst[i] = lo;
    *(ushort2*)&dst[i + 2] = hi;
}

__global__ __launch_bounds__(256) void cast_bf16_w4(
    const float* __restrict__ s0, const float* __restrict__ s1,
    const float* __restrict__ s2, const float* __restrict__ s3,
    unsigned short* __restrict__ d0, unsigned short* __restrict__ d1,
    unsigned short* __restrict__ d2, unsigned short* __restrict__ d3)
{
    const float* s = (blockIdx.y == 0) ? s0 : (blockIdx.y == 1) ? s1
                    : (blockIdx.y == 2) ? s2 : s3;
    unsigned short* d = (blockIdx.y == 0) ? d0 : (blockIdx.y == 1) ? d1
                       : (blockIdx.y == 2) ? d2 : d3;
    int i = (blockIdx.x * 256 + threadIdx.x) * 4;
    float4 v = *(const float4*)&s[i];
    ushort2 lo = {f2bf(v.x), f2bf(v.y)};
    ushort2 hi = {f2bf(v.z), f2bf(v.w)};
    *(ushort2*)&d[i] = lo;
    *(ushort2*)&d[i + 2] = hi;
}

// ---------------------------------------------------------------------------
// MFMA Performer feature map, in place on bf16 rows of 64.
// ---------------------------------------------------------------------------
__global__ __launch_bounds__(256) void featmap_mfma(
    unsigned short* __restrict__ buf, const float* __restrict__ R)
{
    __shared__ unsigned short Rt[64 * 72];
    const int t = threadIdx.x;
    for (int i = t; i < 4096; i += 256) {
        int n = i >> 6, k = i & 63;
        Rt[n * 72 + k] = f2bf(R[k * 64 + n]);
    }
    __syncthreads();

    const int lane = t & 63;
    const int w = t >> 6;
    const size_t rowbase = (size_t)blockIdx.x * 256 + w * 64;
    const int fr = lane & 15;
    const int fq = (lane >> 4) * 8;

    f32x4 acc[4][4] = {};
    float sqacc[4] = {0.f, 0.f, 0.f, 0.f};

#pragma unroll
    for (int ks = 0; ks < 2; ks++) {
        bf16x8 bfr[4];
#pragma unroll
        for (int nt = 0; nt < 4; nt++)
            bfr[nt] = *(const bf16x8*)&Rt[(nt * 16 + fr) * 72 + ks * 32 + fq];
#pragma unroll
        for (int mt = 0; mt < 4; mt++) {
            bf16x8 a = *(const bf16x8*)
                &buf[(rowbase + mt * 16 + fr) * 64 + ks * 32 + fq];
#pragma unroll
            for (int j = 0; j < 8; j++) {
                float v = bf2f((unsigned short)a[j]);
                sqacc[mt] = fmaf(v, v, sqacc[mt]);
            }
#pragma unroll
            for (int nt = 0; nt < 4; nt++)
                acc[mt][nt] = __builtin_amdgcn_mfma_f32_16x16x32_bf16(
                    a, bfr[nt], acc[mt][nt], 0, 0, 0);
        }
    }
#pragma unroll
    for (int mt = 0; mt < 4; mt++) {
        sqacc[mt] += __shfl_xor(sqacc[mt], 16);
        sqacc[mt] += __shfl_xor(sqacc[mt], 32);
    }

    const int col = lane & 15;
    const int rq  = (lane >> 4) * 4;
#pragma unroll
    for (int mt = 0; mt < 4; mt++) {
#pragma unroll
        for (int r = 0; r < 4; r++) {
            float s = __shfl(sqacc[mt], rq + r);
            size_t row = rowbase + mt * 16 + rq + r;
#pragma unroll
            for (int nt = 0; nt < 4; nt++) {
                float val = acc[mt][nt][r] * 0.125f - s * 0.0078125f;
                buf[row * 64 + nt * 16 + col] = f2bf(__expf(val));
            }
        }
    }
}

// ---------------------------------------------------------------------------
// kv[b,h,m,e] += sum_n k'[n,m] * v[n,e] over a 512-token chunk. bf16 in.
// ---------------------------------------------------------------------------
__global__ __launch_bounds__(256) void kv_accum(
    const unsigned short* __restrict__ kp, const unsigned short* __restrict__ vp,
    float* __restrict__ kv)
{
    __shared__ float Ks[16][68];
    __shared__ float Vs[16][68];
    const int chunk = blockIdx.x;
    const int h = blockIdx.y;
    const int b = blockIdx.z;
    const int t = threadIdx.x;
    const int tx = t & 15, ty = t >> 4;
    float c[4][4] = {};
    const int nbase = b * SEQ + chunk * 512;
    const int nl = t >> 4, seg = t & 15;
    for (int n0 = 0; n0 < 512; n0 += 16) {
        size_t gaddr = (size_t)(nbase + n0 + nl) * DIM + h * 64 + seg * 4;
        ushort4 kq = *(const ushort4*)&kp[gaddr];
        ushort4 vq = *(const ushort4*)&vp[gaddr];
        Ks[nl][seg * 4 + 0] = bf2f(kq.x); Ks[nl][seg * 4 + 1] = bf2f(kq.y);
        Ks[nl][seg * 4 + 2] = bf2f(kq.z); Ks[nl][seg * 4 + 3] = bf2f(kq.w);
        Vs[nl][seg * 4 + 0] = bf2f(vq.x); Vs[nl][seg * 4 + 1] = bf2f(vq.y);
        Vs[nl][seg * 4 + 2] = bf2f(vq.z); Vs[nl][seg * 4 + 3] = bf2f(vq.w);
        __syncthreads();
#pragma unroll
        for (int nn = 0; nn < 16; nn++) {
            float4 a = *(const float4*)&Ks[nn][ty * 4];
            float4 bq = *(const float4*)&Vs[nn][tx * 4];
            float aa[4] = {a.x, a.y, a.z, a.w};
            float bb[4] = {bq.x, bq.y, bq.z, bq.w};
#pragma unroll
            for (int i = 0; i < 4; i++)
#pragma unroll
                for (int j = 0; j < 4; j++)
                    c[i][j] += aa[i] * bb[j];
        }
        __syncthreads();
    }
    float* dst = &kv[(size_t)(b * NH + h) * 64 * 64];
#pragma unroll
    for (int i = 0; i < 4; i++)
#pragma unroll
        for (int j = 0; j < 4; j++)
            atomicAdd(&dst[(ty * 4 + i) * 64 + tx * 4 + j], c[i][j]);
}

// ---------------------------------------------------------------------------
// MFMA attn out: per (b,h), out[n,e] = z[n] * (q'[n,:] @ kv[:,e])
// ---------------------------------------------------------------------------
__global__ __launch_bounds__(256) void attn_out_mfma(
    const unsigned short* __restrict__ qp, const float* __restrict__ kv,
    unsigned short* __restrict__ ob)
{
    __shared__ unsigned short kvT[64 * 72];
    const int t = threadIdx.x;
    const int bh = blockIdx.y;
    const int b = bh >> 4, h = bh & 15;
    const float* kvp = &kv[(size_t)bh * 4096];
    for (int i = t; i < 4096; i += 256) {
        int m = i >> 6, e = i & 63;
        kvT[e * 72 + m] = f2bf(kvp[i]);
    }
    __syncthreads();

    const int lane = t & 63;
    const int w = t >> 6;
    const int rowInSeq = blockIdx.x * 256 + w * 64;
    const int fr = lane & 15;
    const int fq = (lane >> 4) * 8;

    f32x4 acc[4][4] = {};
    float rsum[4] = {0.f, 0.f, 0.f, 0.f};

#pragma unroll
    for (int ks = 0; ks < 2; ks++) {
        bf16x8 bfr[4];
#pragma unroll
        for (int nt = 0; nt < 4; nt++)
            bfr[nt] = *(const bf16x8*)&kvT[(nt * 16 + fr) * 72 + ks * 32 + fq];
#pragma unroll
        for (int mt = 0; mt < 4; mt++) {
            size_t n = (size_t)(b * SEQ + rowInSeq + mt * 16 + fr);
            bf16x8 a = *(const bf16x8*)&qp[n * DIM + h * 64 + ks * 32 + fq];
#pragma unroll
            for (int j = 0; j < 8; j++)
                rsum[mt] += bf2f((unsigned short)a[j]);
#pragma unroll
            for (int nt = 0; nt < 4; nt++)
                acc[mt][nt] = __builtin_amdgcn_mfma_f32_16x16x32_bf16(
                    a, bfr[nt], acc[mt][nt], 0, 0, 0);
        }
    }
#pragma unroll
    for (int mt = 0; mt < 4; mt++) {
        rsum[mt] += __shfl_xor(rsum[mt], 16);
        rsum[mt] += __shfl_xor(rsum[mt], 32);
    }

    const int col = lane & 15;
    const int rq  = (lane >> 4) * 4;
#pragma unroll
    for (int mt = 0; mt < 4; mt++) {
#pragma unroll
        for (int r = 0; r < 4; r++) {
            float s = __shfl(rsum[mt], rq + r);
            float z = 1.f / (s + 1e-8f);
            size_t n = (size_t)(b * SEQ + rowInSeq + mt * 16 + rq + r);
#pragma unroll
            for (int nt = 0; nt < 4; nt++)
                ob[n * DIM + h * 64 + nt * 16 + col] = f2bf(acc[mt][nt][r] * z);
        }
    }
}

extern "C" void kernel_launch(void* const* d_in, const int* in_sizes, int n_in,
                              void* d_out, int out_size, void* d_ws, size_t ws_size,
                              hipStream_t stream) {
    const float* x  = (const float*)d_in[0];
    const float* Wq = (const float*)d_in[1];
    const float* bq = (const float*)d_in[2];
    const float* Wk = (const float*)d_in[3];
    const float* bk = (const float*)d_in[4];
    const float* Wv = (const float*)d_in[5];
    const float* bv = (const float*)d_in[6];
    const float* Wo = (const float*)d_in[7];
    const float* bo = (const float*)d_in[8];
    const float* R  = (const float*)d_in[9];
    float* out = (float*)d_out;

    // workspace — 137 MB. qb/kb contiguous (featmap spans both).
    char* p = (char*)d_ws;
    unsigned short* xb = (unsigned short*)p; p += (size_t)NTOK * DIM * 2;  // 32MB
    unsigned short* qb = (unsigned short*)p; p += (size_t)NTOK * DIM * 2;  // 32MB
    unsigned short* kb = (unsigned short*)p; p += (size_t)NTOK * DIM * 2;  // 32MB
    unsigned short* vb = (unsigned short*)p; p += (size_t)NTOK * DIM * 2;  // 32MB
    float* kvb = (float*)p;                  p += (size_t)BATCH * NH * HD * HD * 4; // 1MB
    unsigned short* wqkv = (unsigned short*)p; p += (size_t)3 * DIM * DIM * 2; // 6MB contig
    unsigned short* wob  = (unsigned short*)p; p += (size_t)DIM * DIM * 2;     // 2MB

    hipMemsetAsync(kvb, 0, (size_t)BATCH * NH * HD * HD * sizeof(float), stream);

    cast_bf16<<<NTOK * DIM / (256 * 4), 256, 0, stream>>>(x, xb, NTOK * DIM);
    cast_bf16_w4<<<dim3(DIM * DIM / (256 * 4), 4), 256, 0, stream>>>(
        Wq, Wk, Wv, Wo,
        wqkv, wqkv + (size_t)DIM * DIM, wqkv + (size_t)2 * DIM * DIM, wob);

    // fused QKV projection: 24 n-blocks x 128 m-tiles = 3072 blocks
    gemm_swz<24, 1><<<3072, 256, 0, stream>>>(
        xb, wqkv, bq, bk, bv, qb, kb, vb);

    // feature map over q' and k' in one launch (contiguous rows)
    featmap_mfma<<<2 * NTOK * NH / 256, 256, 0, stream>>>(qb, R);

    kv_accum<<<dim3(8, NH, BATCH), 256, 0, stream>>>(kb, vb, kvb);

    // attn output reuses xb
    attn_out_mfma<<<dim3(SEQ / 256, BATCH * NH), 256, 0, stream>>>(qb, kvb, xb);

    // output projection: 8 x 128 = 1024 blocks, fp32 out
    gemm_swz<8, 0><<<1024, 256, 0, stream>>>(
        xb, wob, bo, bo, bo, out, out, out);
}